// Round 1
// baseline (294.460 us; speedup 1.0000x reference)
//
#include <hip/hip_runtime.h>

#define T_DIM 16384
#define B_DIM 64
#define E_DIM 4096

// ---------------------------------------------------------------------------
// K1: alpha[t], beta[t] = sum over b of params[indices[t,b], :]
// One wave (64 lanes) per t; lane b gathers float2 params[idx]; shuffle-reduce.
// ---------------------------------------------------------------------------
__global__ __launch_bounds__(256) void coeff_kernel(const int* __restrict__ indices,
                                                    const float* __restrict__ params,
                                                    float* __restrict__ alpha,
                                                    float* __restrict__ beta) {
    int gid = blockIdx.x * blockDim.x + threadIdx.x;   // gid = t*64 + b
    int t = gid >> 6;
    int lane = threadIdx.x & 63;
    int idx = indices[gid];
    float2 p = ((const float2*)params)[idx];
    float a = p.x, b = p.y;
    #pragma unroll
    for (int off = 32; off >= 1; off >>= 1) {
        a += __shfl_down(a, off, 64);
        b += __shfl_down(b, off, 64);
    }
    if (lane == 0) { alpha[t] = a; beta[t] = b; }
}

// ---------------------------------------------------------------------------
// K2: inclusive scan of the affine recurrence over T elements, single block.
// compose((a1,b1) earlier, (a2,b2) later) = (a2*a1, a2*b1 + b2); identity (1,0).
// 1024 threads x 16 elements: serial local scan -> block scan -> apply prefix.
// ---------------------------------------------------------------------------
__global__ __launch_bounds__(1024) void scan_kernel(const float* __restrict__ alpha,
                                                    const float* __restrict__ beta,
                                                    float* __restrict__ A,
                                                    float* __restrict__ Bc) {
    __shared__ float sA[1024];
    __shared__ float sB[1024];
    const int tid = threadIdx.x;
    const int base = tid * 16;

    float la[16], lb[16];
    float a = 1.0f, b = 0.0f;
    #pragma unroll
    for (int j = 0; j < 16; ++j) {
        float aj = alpha[base + j];
        float bj = beta[base + j];
        a = aj * a;            // later composes onto earlier state
        b = aj * b + bj;
        la[j] = a; lb[j] = b;
    }
    sA[tid] = a; sB[tid] = b;
    __syncthreads();

    // Hillis-Steele over 1024 thread aggregates (10 steps)
    for (int off = 1; off < 1024; off <<= 1) {
        float pa = 1.0f, pb = 0.0f;
        float ca = sA[tid], cb = sB[tid];
        if (tid >= off) { pa = sA[tid - off]; pb = sB[tid - off]; }
        __syncthreads();
        sA[tid] = ca * pa;          // current(later) o prefix(earlier)
        sB[tid] = ca * pb + cb;
        __syncthreads();
    }

    float pa = 1.0f, pb = 0.0f;
    if (tid > 0) { pa = sA[tid - 1]; pb = sB[tid - 1]; }
    #pragma unroll
    for (int j = 0; j < 16; ++j) {
        A[base + j]  = la[j] * pa;
        Bc[base + j] = la[j] * pb + lb[j];
    }
}

// ---------------------------------------------------------------------------
// K3: out[t, e] = A[t] * M_prev[e] + Bc[t]   (write-BW bound, float4 stores)
// One block per row t; 256 threads x 4 float4 = 4096 floats.
// ---------------------------------------------------------------------------
__global__ __launch_bounds__(256) void out_kernel(const float* __restrict__ A,
                                                  const float* __restrict__ Bc,
                                                  const float* __restrict__ M,
                                                  float* __restrict__ out) {
    const int t = blockIdx.x;
    const float a = A[t];
    const float b = Bc[t];
    const float4* __restrict__ M4 = (const float4*)M;
    float4* __restrict__ O4 = (float4*)(out + (size_t)t * E_DIM);
    const int tid = threadIdx.x;
    #pragma unroll
    for (int k = 0; k < 4; ++k) {
        int e4 = tid + k * 256;
        float4 m = M4[e4];
        float4 r;
        r.x = a * m.x + b;
        r.y = a * m.y + b;
        r.z = a * m.z + b;
        r.w = a * m.w + b;
        O4[e4] = r;
    }
}

extern "C" void kernel_launch(void* const* d_in, const int* in_sizes, int n_in,
                              void* d_out, int out_size, void* d_ws, size_t ws_size,
                              hipStream_t stream) {
    const int*   indices = (const int*)d_in[0];     // (T, B) int -> int32 on device
    const float* M_prev  = (const float*)d_in[1];   // (E,)
    const float* params  = (const float*)d_in[2];   // (N, 2)
    float* out = (float*)d_out;

    float* ws    = (float*)d_ws;
    float* alpha = ws;
    float* beta  = ws + T_DIM;
    float* A     = ws + 2 * T_DIM;
    float* Bc    = ws + 3 * T_DIM;

    coeff_kernel<<<(T_DIM * B_DIM) / 256, 256, 0, stream>>>(indices, params, alpha, beta);
    scan_kernel<<<1, 1024, 0, stream>>>(alpha, beta, A, Bc);
    out_kernel<<<T_DIM, 256, 0, stream>>>(A, Bc, M_prev, out);
}